// Round 7
// baseline (142.312 us; speedup 1.0000x reference)
//
#include <hip/hip_runtime.h>
#include <hip/hip_bf16.h>
#include <math.h>

// ---------------------------------------------------------------------------
// Metric loss (lifted structure) on MI355X.
// R7: ZERO-LDS, barrier-free egemm. Each 64-thread workgroup (= 1 wave)
// computes one 64x64 tile of the triangular Gram via 4x4 16x16x32-bf16
// fragments whose A/B operands are loaded DIRECTLY from global (L2): the
// fragment pattern row=f(l15), k=f(quad) makes each load 16 rows x 64B =
// 16 full cache lines (perfectly coalesced). 2-stage register prefetch
// pipelines L2 latency against MFMA; no __syncthreads anywhere.
// Same math as R4-R6: triangular Gram over 6144 unique rows (text 4096 +
// shape 2048), diag-free partial sums St/Ss, losses reconstructed:
//   tt:  ns = St[2p]+St[2p+1] - 2*exp(1-Dp)
//   st:  ns = G(u1)+G(u2) + e - 2*exp(1-Dp),  G = St + 2*Ss
// ---------------------------------------------------------------------------

typedef __bf16 bf16x8 __attribute__((ext_vector_type(8)));
typedef float floatx4 __attribute__((ext_vector_type(4)));

#define KD 256
#define NU 6144
#define NBU 96                   /* 6144/64 stripes */
#define TU (NBU * (NBU + 1) / 2) /* 4656 */
#define TXB 64                   /* stripes with text rows: s < 64 */
#define ECONST 2.718281828459045f
#define LOSS_BLOCKS 1536

// ---- prep: bf16 convert unique rows, row sq from bf16 ----------------------
__global__ __launch_bounds__(256) void prep_kernel(const float* __restrict__ text,
                                                   const float* __restrict__ shape,
                                                   __bf16* __restrict__ Xu,
                                                   float* __restrict__ sq) {
  int gt = blockIdx.x * 256 + threadIdx.x;
  int wave = gt >> 6;  // one wave per unique row, 0..6143
  int lane = gt & 63;
  const float* src = (wave < 4096) ? (text + (size_t)wave * KD)
                                   : (shape + (size_t)(wave - 4096) * KD);
  __bf16* dst = Xu + (size_t)wave * KD;
  float s = 0.f;
#pragma unroll
  for (int j = 0; j < 4; ++j) {
    int idx = j * 64 + lane;
    float f = src[idx];
    __bf16 h = (__bf16)f;  // RNE
    dst[idx] = h;
    float fv = (float)h;   // square the ROUNDED value (consistency with MFMA G)
    s += fv * fv;
  }
#pragma unroll
  for (int m = 1; m < 64; m <<= 1) s += __shfl_xor(s, m, 64);
  if (lane == 0) sq[wave] = s;
}

// ---- one wave = one 64x64 triangular tile; direct-from-L2 fragments --------
__global__ __launch_bounds__(64, 3) void egemm_tri_kernel(
    const __bf16* __restrict__ X, const float* __restrict__ sq,
    float* __restrict__ rowpart, float* __restrict__ colpart) {
  // triangular decode: by >= bx over 96
  const int t = blockIdx.x;
  int by = (int)((sqrtf(8.0f * (float)t + 1.0f) - 1.0f) * 0.5f);
  while ((by + 1) * (by + 2) / 2 <= t) ++by;
  while (by * (by + 1) / 2 > t) --by;
  const int bx = t - by * (by + 1) / 2;

  const int mBase = by * 64;  // rows (mBase >= nBase)
  const int nBase = bx * 64;  // cols
  const bool diag = (by == bx);

  const int lane = threadIdx.x & 63;
  const int quad = lane >> 4;
  const int l15 = lane & 15;

  // fragment base pointers: one row per l15 per 16-row group
  const bf16x8* arow[4];
  const bf16x8* brow[4];
#pragma unroll
  for (int f = 0; f < 4; ++f) {
    arow[f] = (const bf16x8*)(X + (size_t)(mBase + f * 16 + l15) * KD);
    brow[f] = (const bf16x8*)(X + (size_t)(nBase + f * 16 + l15) * KD);
  }

  floatx4 acc[4][4] = {};
  bf16x8 afr[2][4], bfr[2][4];
#pragma unroll
  for (int f = 0; f < 4; ++f) {  // prefetch kt=0
    afr[0][f] = arow[f][quad];
    bfr[0][f] = brow[f][quad];
  }
#pragma unroll
  for (int kt = 0; kt < 8; ++kt) {
    const int cur = kt & 1;
    if (kt < 7) {
#pragma unroll
      for (int f = 0; f < 4; ++f) {  // prefetch kt+1 while computing kt
        afr[cur ^ 1][f] = arow[f][(kt + 1) * 4 + quad];
        bfr[cur ^ 1][f] = brow[f][(kt + 1) * 4 + quad];
      }
    }
#pragma unroll
    for (int tm = 0; tm < 4; ++tm)
#pragma unroll
      for (int tn = 0; tn < 4; ++tn)
        acc[tm][tn] = __builtin_amdgcn_mfma_f32_16x16x32_bf16(afr[cur][tm], bfr[cur][tn],
                                                              acc[tm][tn], 0, 0, 0);
  }

  // ---- epilogue: E = exp(1-D), diag-free row+col sums (wave-local) ----
  float sqr[4][4], sqc[4];
#pragma unroll
  for (int tm = 0; tm < 4; ++tm)
#pragma unroll
    for (int r = 0; r < 4; ++r)
      sqr[tm][r] = sq[mBase + tm * 16 + quad * 4 + r];
#pragma unroll
  for (int tn = 0; tn < 4; ++tn)
    sqc[tn] = sq[nBase + tn * 16 + l15];

  const float L2E = 1.44269504088896f;
  float cs[4] = {0.f, 0.f, 0.f, 0.f};
#pragma unroll
  for (int tm = 0; tm < 4; ++tm) {
    float rs[4] = {0.f, 0.f, 0.f, 0.f};
#pragma unroll
    for (int tn = 0; tn < 4; ++tn) {
#pragma unroll
      for (int r = 0; r < 4; ++r) {
        float v = acc[tm][tn][r];
        float dsq = fmaf(-2.0f, v, sqr[tm][r] + sqc[tn]);
        float dst = sqrtf(fmaxf(dsq, 0.f));
        float ev = __builtin_amdgcn_exp2f(fmaf(-L2E, dst, L2E));
        // unique-level diagonal excluded (handled analytically downstream);
        // tm==tn is compile-time, so only 4 frag-pairs carry the cndmask
        if (tm == tn && diag && (quad * 4 + r) == l15) ev = 0.f;
        rs[r] += ev;
        cs[tn] += ev;
      }
    }
#pragma unroll
    for (int r = 0; r < 4; ++r) {
      float v = rs[r];
      v += __shfl_xor(v, 1, 64);
      v += __shfl_xor(v, 2, 64);
      v += __shfl_xor(v, 4, 64);
      v += __shfl_xor(v, 8, 64);  // sum the 16 cols of this quad's row
      if (l15 == 0) rowpart[(size_t)t * 64 + tm * 16 + quad * 4 + r] = v;
    }
  }
#pragma unroll
  for (int tn = 0; tn < 4; ++tn) {
    float v = cs[tn];
    v += __shfl_xor(v, 16, 64);
    v += __shfl_xor(v, 32, 64);  // sum over the 4 quads (all 64 rows)
    if (quad == 0) colpart[(size_t)t * 64 + tn * 16 + l15] = diag ? 0.f : v;
  }
}

// ---- gather per-block partials -> St / Ss (plain stores) -------------------
__global__ __launch_bounds__(256) void rowreduce_kernel(const float* __restrict__ rowpart,
                                                        const float* __restrict__ colpart,
                                                        float* __restrict__ rowacc) {
  // one thread per unique row: u = s*64 + r
  const int u = blockIdx.x * 256 + threadIdx.x;
  const int s = u >> 6;
  const int r = u & 63;
  float stv = 0.f, ssv = 0.f;
  const int base = s * (s + 1) / 2;
  // row contributions from tiles (by=s, bx=0..s): cols text iff bx<64
  for (int bx = 0; bx <= s; ++bx) {
    float v = rowpart[(size_t)(base + bx) * 64 + r];
    if (bx < TXB) stv += v; else ssv += v;
  }
  // col contributions from tiles (by=s+1..95, bx=s): rows text iff by<64
  for (int by = s + 1; by < NBU; ++by) {
    float v = colpart[(size_t)(by * (by + 1) / 2 + s) * 64 + r];
    if (by < TXB) stv += v; else ssv += v;
  }
  rowacc[u] = stv;       // St
  rowacc[NU + u] = ssv;  // Ss
}

// ---- per-pair fp32 distance + analytic ns + J; block partials --------------
__global__ __launch_bounds__(256) void loss_kernel(const float* __restrict__ text,
                                                   const float* __restrict__ shape,
                                                   const float* __restrict__ rowacc,
                                                   float* __restrict__ partials) {
  __shared__ float part[4];
  const float* St = rowacc;
  const float* Ss = rowacc + NU;
  int wv = blockIdx.x * 4 + (threadIdx.x >> 6);  // one wave per pair, 0..6143
  int lane = threadIdx.x & 63;
  const float *a, *b;
  float base, scale;
  if (wv < 2048) {  // tt pair p
    int p = wv;
    a = text + (size_t)(2 * p) * KD;
    b = text + (size_t)(2 * p + 1) * KD;
    base = St[2 * p] + St[2 * p + 1];
    scale = 1.0f / 4096.0f;
  } else {  // st pair
    int p = wv - 2048;
    int u1, u2;
    if (p < 2048) {  // (text_2p, shape_p)
      u1 = 2 * p; u2 = 4096 + p;
      a = text + (size_t)(2 * p) * KD;
      b = shape + (size_t)p * KD;
    } else {         // (shape_s, text_{2s+1})
      int s = p - 2048;
      u1 = 4096 + s; u2 = 2 * s + 1;
      a = shape + (size_t)s * KD;
      b = text + (size_t)(2 * s + 1) * KD;
    }
    float g1 = St[u1] + 2.0f * Ss[u1];
    float g2 = St[u2] + 2.0f * Ss[u2];
    base = g1 + g2 + ECONST;
    scale = 1.0f / 8192.0f;
  }
  float s = 0.f;
#pragma unroll
  for (int j = 0; j < 4; ++j) {
    int idx = j * 64 + lane;
    float d = a[idx] - b[idx];
    s += d * d;
  }
#pragma unroll
  for (int m = 1; m < 64; m <<= 1) s += __shfl_xor(s, m, 64);
  if (lane == 0) {
    float D = s > 0.f ? sqrtf(s) : 0.f;
    float ns = base - 2.0f * expf(1.0f - D);
    float J = logf(ns) + D;
    part[threadIdx.x >> 6] = (J > 0.f) ? J * J * scale : 0.f;
  }
  __syncthreads();
  if (threadIdx.x == 0)
    partials[blockIdx.x] = part[0] + part[1] + part[2] + part[3];
}

// ---- final: sum partials -> out[0] ----------------------------------------
__global__ __launch_bounds__(256) void reduce_kernel(const float* __restrict__ partials,
                                                     float* __restrict__ out, int out_n) {
  __shared__ float part[4];
  float s = 0.f;
  for (int i = threadIdx.x; i < LOSS_BLOCKS; i += 256) s += partials[i];
#pragma unroll
  for (int m = 1; m < 64; m <<= 1) s += __shfl_xor(s, m, 64);
  if ((threadIdx.x & 63) == 0) part[threadIdx.x >> 6] = s;
  __syncthreads();
  if (threadIdx.x == 0) out[0] = part[0] + part[1] + part[2] + part[3];
  else if (threadIdx.x < out_n) out[threadIdx.x] = 0.f;
}

extern "C" void kernel_launch(void* const* d_in, const int* in_sizes, int n_in,
                              void* d_out, int out_size, void* d_ws, size_t ws_size,
                              hipStream_t stream) {
  const float* text = (const float*)d_in[0];
  const float* shape = (const float*)d_in[1];
  float* out = (float*)d_out;

  char* ws = (char*)d_ws;
  __bf16* Xu = (__bf16*)ws;                        // 3 MB
  float* sq = (float*)(ws + (size_t)NU * KD * 2);  // 24 KB
  float* rowacc = sq + NU;                         // 48 KB (St ++ Ss)
  float* partials = rowacc + 2 * NU;               // 6 KB
  float* rowpart = partials + LOSS_BLOCKS;         // 1.19 MB
  float* colpart = rowpart + (size_t)TU * 64;      // 1.19 MB

  prep_kernel<<<NU / 4, 256, 0, stream>>>(text, shape, Xu, sq);
  egemm_tri_kernel<<<TU, 64, 0, stream>>>(Xu, sq, rowpart, colpart);
  rowreduce_kernel<<<NU / 256, 256, 0, stream>>>(rowpart, colpart, rowacc);
  loss_kernel<<<LOSS_BLOCKS, 256, 0, stream>>>(text, shape, rowacc, partials);
  reduce_kernel<<<1, 256, 0, stream>>>(partials, out, out_size);
}

// Round 8
// 126.077 us; speedup vs baseline: 1.1288x; 1.1288x over previous
//
#include <hip/hip_runtime.h>
#include <hip/hip_bf16.h>
#include <math.h>

// ---------------------------------------------------------------------------
// Metric loss (lifted structure) on MI355X.
// R8: FRAGMENT-MAJOR data layout. prep stores Xf[g][kt][lane] = the 16B each
// lane needs for MFMA fragment (row-group g, k-chunk kt), so every egemm load
// is one fully-contiguous 1KB global_load_dwordx4 (vs 16 scattered 64B
// segments in R4-R7, which all plateaued at ~4-6 TB/s effective L2 rate).
// 2x2 super-tiles: 4 waves/wg share 32KB panels pairwise (L1 captures the
// second reader). No LDS, no barriers; 2-deep register prefetch under
// launch_bounds(256,3) (VGPR cap 170).
// Math unchanged (R4-R7): triangular Gram over 6144 unique rows, diag-free
// partial sums St/Ss, losses reconstructed analytically:
//   tt:  ns = St[2p]+St[2p+1] - 2*exp(1-Dp)
//   st:  ns = G(u1)+G(u2) + e - 2*exp(1-Dp),  G = St + 2*Ss
// ---------------------------------------------------------------------------

typedef __bf16 bf16x8 __attribute__((ext_vector_type(8)));
typedef float floatx4 __attribute__((ext_vector_type(4)));

#define KD 256
#define NU 6144
#define NBU 96                    /* 64-row stripes */
#define TU (NBU * (NBU + 1) / 2)  /* 4656 canonical tiles */
#define NBS 48                    /* 128-row super stripes */
#define TSUP (NBS * (NBS + 1) / 2) /* 1176 super tiles */
#define TXB 64                    /* stripes with text rows: s < 64 */
#define ECONST 2.718281828459045f
#define LOSS_BLOCKS 1536

// ---- prep: convert to bf16 FRAGMENT-MAJOR layout + row sq ------------------
// Xf index: ((g*8 + kt)*64 + lane) 16B-chunks; lane=(quad,l15) holds
// X[16g+l15][kt*32+quad*8 .. +8].  g = row/16 (384 groups; text g<256).
__global__ __launch_bounds__(256) void prep_kernel(const float* __restrict__ text,
                                                   const float* __restrict__ shape,
                                                   __bf16* __restrict__ Xf,
                                                   float* __restrict__ sq) {
  const int g = blockIdx.x * 4 + (threadIdx.x >> 6);  // group 0..383
  const int lane = threadIdx.x & 63;
  const int quad = lane >> 4, l15 = lane & 15;
  const int row = g * 16 + l15;
  const float* src = (row < 4096) ? text + (size_t)row * KD
                                  : shape + (size_t)(row - 4096) * KD;
  bf16x8* Xv = (bf16x8*)Xf;
  float s = 0.f;
#pragma unroll
  for (int kt = 0; kt < 8; ++kt) {
    const float4* p = (const float4*)(src + kt * 32 + quad * 8);
    float4 f0 = p[0], f1 = p[1];
    bf16x8 h;
    h[0] = (__bf16)f0.x; h[1] = (__bf16)f0.y; h[2] = (__bf16)f0.z; h[3] = (__bf16)f0.w;
    h[4] = (__bf16)f1.x; h[5] = (__bf16)f1.y; h[6] = (__bf16)f1.z; h[7] = (__bf16)f1.w;
    Xv[(g * 8 + kt) * 64 + lane] = h;  // contiguous 1KB store per (g,kt)
#pragma unroll
    for (int j = 0; j < 8; ++j) {  // square the ROUNDED value (consistency)
      float fv = (float)h[j];
      s = fmaf(fv, fv, s);
    }
  }
  s += __shfl_xor(s, 16, 64);  // sum the 4 quads -> full row sum
  s += __shfl_xor(s, 32, 64);
  if (lane < 16) sq[g * 16 + lane] = s;
}

// ---- 2x2 super-tile egemm: 4 waves, each one 64x64 tile, zero LDS ---------
__global__ __launch_bounds__(256, 3) void egemm_tri_kernel(
    const __bf16* __restrict__ Xf, const float* __restrict__ sq,
    float* __restrict__ rowpart, float* __restrict__ colpart) {
  // super-tile decode over tri(48): BY >= BX
  const int ts = blockIdx.x;
  int BY = (int)((sqrtf(8.0f * (float)ts + 1.0f) - 1.0f) * 0.5f);
  while ((BY + 1) * (BY + 2) / 2 <= ts) ++BY;
  while (BY * (BY + 1) / 2 > ts) --BY;
  const int BX = ts - BY * (BY + 1) / 2;

  const int w = threadIdx.x >> 6;
  const int lane = threadIdx.x & 63;
  const int quad = lane >> 4, l15 = lane & 15;

  int by = 2 * BY + (w >> 1);
  int bx = 2 * BX + (w & 1);
  const bool dup = bx > by;  // only on diag supers (w==1): duplicate tile
  if (dup) bx = by;          // compute something harmless, write to garbage
  const bool diag = (by == bx);
  const int tslot = dup ? TU : by * (by + 1) / 2 + bx;

  // fragment pointers (16B units): frag(tm,kt) = aB[tm*512 + kt*64]
  const bf16x8* aB = (const bf16x8*)Xf + (size_t)by * 2048 + lane;
  const bf16x8* bB = (const bf16x8*)Xf + (size_t)bx * 2048 + lane;

  floatx4 acc[4][4] = {};
  bf16x8 afr[2][4], bfr[2][4];
#pragma unroll
  for (int f = 0; f < 4; ++f) {  // prefetch kt=0 (contiguous 1KB loads)
    afr[0][f] = aB[f * 512];
    bfr[0][f] = bB[f * 512];
  }
#pragma unroll
  for (int kt = 0; kt < 8; ++kt) {
    const int cur = kt & 1;
    if (kt < 7) {
#pragma unroll
      for (int f = 0; f < 4; ++f) {  // prefetch kt+1 while computing kt
        afr[cur ^ 1][f] = aB[f * 512 + (kt + 1) * 64];
        bfr[cur ^ 1][f] = bB[f * 512 + (kt + 1) * 64];
      }
    }
#pragma unroll
    for (int tm = 0; tm < 4; ++tm)
#pragma unroll
      for (int tn = 0; tn < 4; ++tn)
        acc[tm][tn] = __builtin_amdgcn_mfma_f32_16x16x32_bf16(afr[cur][tm], bfr[cur][tn],
                                                              acc[tm][tn], 0, 0, 0);
  }

  // ---- epilogue: E = exp(1-D), diag-free row+col sums (wave-local) ----
  const int mBase = by * 64, nBase = bx * 64;
  float sqr[4][4], sqc[4];
#pragma unroll
  for (int tm = 0; tm < 4; ++tm)
#pragma unroll
    for (int r = 0; r < 4; ++r)
      sqr[tm][r] = sq[mBase + tm * 16 + quad * 4 + r];
#pragma unroll
  for (int tn = 0; tn < 4; ++tn)
    sqc[tn] = sq[nBase + tn * 16 + l15];

  const float L2E = 1.44269504088896f;
  float cs[4] = {0.f, 0.f, 0.f, 0.f};
#pragma unroll
  for (int tm = 0; tm < 4; ++tm) {
    float rs[4] = {0.f, 0.f, 0.f, 0.f};
#pragma unroll
    for (int tn = 0; tn < 4; ++tn) {
#pragma unroll
      for (int r = 0; r < 4; ++r) {
        float v = acc[tm][tn][r];
        float dsq = fmaf(-2.0f, v, sqr[tm][r] + sqc[tn]);
        float dst = sqrtf(fmaxf(dsq, 0.f));
        float ev = __builtin_amdgcn_exp2f(fmaf(-L2E, dst, L2E));
        // unique-level diagonal excluded (handled analytically downstream)
        if (tm == tn && diag && (quad * 4 + r) == l15) ev = 0.f;
        rs[r] += ev;
        cs[tn] += ev;
      }
    }
#pragma unroll
    for (int r = 0; r < 4; ++r) {
      float v = rs[r];
      v += __shfl_xor(v, 1, 64);
      v += __shfl_xor(v, 2, 64);
      v += __shfl_xor(v, 4, 64);
      v += __shfl_xor(v, 8, 64);  // sum the 16 cols of this quad's row
      if (l15 == 0) rowpart[(size_t)tslot * 64 + tm * 16 + quad * 4 + r] = v;
    }
  }
#pragma unroll
  for (int tn = 0; tn < 4; ++tn) {
    float v = cs[tn];
    v += __shfl_xor(v, 16, 64);
    v += __shfl_xor(v, 32, 64);  // sum over the 4 quads (all 64 rows)
    if (quad == 0) colpart[(size_t)tslot * 64 + tn * 16 + l15] = diag ? 0.f : v;
  }
}

// ---- gather per-tile partials -> St / Ss (plain stores) --------------------
__global__ __launch_bounds__(256) void rowreduce_kernel(const float* __restrict__ rowpart,
                                                        const float* __restrict__ colpart,
                                                        float* __restrict__ rowacc) {
  // one thread per unique row: u = s*64 + r
  const int u = blockIdx.x * 256 + threadIdx.x;
  const int s = u >> 6;
  const int r = u & 63;
  float stv = 0.f, ssv = 0.f;
  const int base = s * (s + 1) / 2;
  // row contributions from tiles (by=s, bx=0..s): cols text iff bx<64
  for (int bx = 0; bx <= s; ++bx) {
    float v = rowpart[(size_t)(base + bx) * 64 + r];
    if (bx < TXB) stv += v; else ssv += v;
  }
  // col contributions from tiles (by=s+1..95, bx=s): rows text iff by<64
  for (int by = s + 1; by < NBU; ++by) {
    float v = colpart[(size_t)(by * (by + 1) / 2 + s) * 64 + r];
    if (by < TXB) stv += v; else ssv += v;
  }
  rowacc[u] = stv;       // St
  rowacc[NU + u] = ssv;  // Ss
}

// ---- per-pair fp32 distance + analytic ns + J; block partials --------------
__global__ __launch_bounds__(256) void loss_kernel(const float* __restrict__ text,
                                                   const float* __restrict__ shape,
                                                   const float* __restrict__ rowacc,
                                                   float* __restrict__ partials) {
  __shared__ float part[4];
  const float* St = rowacc;
  const float* Ss = rowacc + NU;
  int wv = blockIdx.x * 4 + (threadIdx.x >> 6);  // one wave per pair, 0..6143
  int lane = threadIdx.x & 63;
  const float *a, *b;
  float base, scale;
  if (wv < 2048) {  // tt pair p
    int p = wv;
    a = text + (size_t)(2 * p) * KD;
    b = text + (size_t)(2 * p + 1) * KD;
    base = St[2 * p] + St[2 * p + 1];
    scale = 1.0f / 4096.0f;
  } else {  // st pair
    int p = wv - 2048;
    int u1, u2;
    if (p < 2048) {  // (text_2p, shape_p)
      u1 = 2 * p; u2 = 4096 + p;
      a = text + (size_t)(2 * p) * KD;
      b = shape + (size_t)p * KD;
    } else {         // (shape_s, text_{2s+1})
      int s = p - 2048;
      u1 = 4096 + s; u2 = 2 * s + 1;
      a = shape + (size_t)s * KD;
      b = text + (size_t)(2 * s + 1) * KD;
    }
    float g1 = St[u1] + 2.0f * Ss[u1];
    float g2 = St[u2] + 2.0f * Ss[u2];
    base = g1 + g2 + ECONST;
    scale = 1.0f / 8192.0f;
  }
  float s = 0.f;
#pragma unroll
  for (int j = 0; j < 4; ++j) {
    int idx = j * 64 + lane;
    float d = a[idx] - b[idx];
    s += d * d;
  }
#pragma unroll
  for (int m = 1; m < 64; m <<= 1) s += __shfl_xor(s, m, 64);
  if (lane == 0) {
    float D = s > 0.f ? sqrtf(s) : 0.f;
    float ns = base - 2.0f * expf(1.0f - D);
    float J = logf(ns) + D;
    part[threadIdx.x >> 6] = (J > 0.f) ? J * J * scale : 0.f;
  }
  __syncthreads();
  if (threadIdx.x == 0)
    partials[blockIdx.x] = part[0] + part[1] + part[2] + part[3];
}

// ---- final: sum partials -> out[0] ----------------------------------------
__global__ __launch_bounds__(256) void reduce_kernel(const float* __restrict__ partials,
                                                     float* __restrict__ out, int out_n) {
  __shared__ float part[4];
  float s = 0.f;
  for (int i = threadIdx.x; i < LOSS_BLOCKS; i += 256) s += partials[i];
#pragma unroll
  for (int m = 1; m < 64; m <<= 1) s += __shfl_xor(s, m, 64);
  if ((threadIdx.x & 63) == 0) part[threadIdx.x >> 6] = s;
  __syncthreads();
  if (threadIdx.x == 0) out[0] = part[0] + part[1] + part[2] + part[3];
  else if (threadIdx.x < out_n) out[threadIdx.x] = 0.f;
}

extern "C" void kernel_launch(void* const* d_in, const int* in_sizes, int n_in,
                              void* d_out, int out_size, void* d_ws, size_t ws_size,
                              hipStream_t stream) {
  const float* text = (const float*)d_in[0];
  const float* shape = (const float*)d_in[1];
  float* out = (float*)d_out;

  char* ws = (char*)d_ws;
  __bf16* Xf = (__bf16*)ws;                        // 3 MB (fragment-major)
  float* sq = (float*)(ws + (size_t)NU * KD * 2);  // 24 KB
  float* rowacc = sq + NU;                         // 48 KB (St ++ Ss)
  float* partials = rowacc + 2 * NU;               // 6 KB
  float* rowpart = partials + LOSS_BLOCKS;         // (TU+1)*64 floats
  float* colpart = rowpart + (size_t)(TU + 1) * 64;

  prep_kernel<<<96, 256, 0, stream>>>(text, shape, Xf, sq);
  egemm_tri_kernel<<<TSUP, 256, 0, stream>>>(Xf, sq, rowpart, colpart);
  rowreduce_kernel<<<NU / 256, 256, 0, stream>>>(rowpart, colpart, rowacc);
  loss_kernel<<<LOSS_BLOCKS, 256, 0, stream>>>(text, shape, rowacc, partials);
  reduce_kernel<<<1, 256, 0, stream>>>(partials, out, out_size);
}